// Round 12
// baseline (301.728 us; speedup 1.0000x reference)
//
#include <hip/hip_runtime.h>
#include <hip/hip_bf16.h>
#include <math.h>

#define THREADS 256
#define MTHREADS 512
typedef unsigned short ushortT;
typedef __attribute__((ext_vector_type(8))) short bf16x8;   // 8 bf16 = 4 VGPRs
typedef __attribute__((ext_vector_type(4))) float f32x4;

__device__ __forceinline__ void async16(const ushortT* g, ushortT* l) {
  __builtin_amdgcn_global_load_lds(
      (const __attribute__((address_space(1))) unsigned int*)g,
      (__attribute__((address_space(3))) unsigned int*)l, 16, 0, 0);
}

__device__ __forceinline__ ushortT f2bf(float f) {
  __hip_bfloat16 h = __float2bfloat16(f);
  return *reinterpret_cast<ushortT*>(&h);
}

// ---------------------------------------------------------------------------
// Kernel A: fused L2-norm + bf16 convert. One block per row (256 thr x float4).
// ---------------------------------------------------------------------------
__global__ __launch_bounds__(THREADS) void k_prep(const float* __restrict__ x,
                                                  ushortT* __restrict__ xn, int D) {
  __shared__ float red[4];
  const int row = blockIdx.x;
  const int tid = threadIdx.x;
  const int gid = row * (D / 4) + tid;
  const float4 v = reinterpret_cast<const float4*>(x)[gid];
  float s = v.x * v.x + v.y * v.y + v.z * v.z + v.w * v.w;
  #pragma unroll
  for (int off = 32; off; off >>= 1) s += __shfl_xor(s, off);
  if ((tid & 63) == 0) red[tid >> 6] = s;
  __syncthreads();
  const float tot = red[0] + red[1] + red[2] + red[3];
  const float rn = 1.0f / fmaxf(sqrtf(tot), 1e-12f);
  ushort4 o;
  o.x = f2bf(v.x * rn); o.y = f2bf(v.y * rn);
  o.z = f2bf(v.z * rn); o.w = f2bf(v.w * rn);
  reinterpret_cast<ushort4*>(xn)[gid] = o;
}

// ---------------------------------------------------------------------------
// Kernel B: triangular 256x256 bf16 MFMA tiles, 8 waves (512 thr), BK=64,
// 2-phase (stage-next before compute, ONE __syncthreads per K-tile).
//
// Model (R11 post-mortem): k_main is VMEM-delivery-bound. 128² tiles stage
// 1.05 GB through global_load_lds; at the ~10 B/cyc/CU delivery ceiling
// (6.2 TB/s chip) that is exactly R9's 169 us. 256² halves staged bytes to
// 528 MB -> ~86 us floor. R10/R11 failed ONLY on a register spill (WRITE 60
// MB): the fully-unrolled trip-2 s-loop was software-pipelined, putting both
// sub-iterations' fragment sets + dup address chains live on top of 128 acc.
// Fix this round (minimal diff from correctness-verified R11):
//   1. #pragma unroll 1 on the s-loop (s never indexes a register array ->
//      no scratch risk; kills cross-s liveness).
//   2. sched_barrier(0) after stage-issue (bounds scheduler liveness bleed;
//      issue-early overlap preserved).
// PASS/FAIL: WRITE_SIZE ~16.4 MB. Still >20 MB -> revert to R9 for good.
//
// Geometry: nb = B/256 = 32, grid 528. Wave w: wr2=w>>2 (128-row half),
// wc2=w&3 (64-col quarter); acc[8][4]. LDS dbuf x (A 32K + B 32K) = 128 KB.
// Layout [buf][group(16 rows)][ksub(2)][512], fragment-read order.
// Epilogue -> partial (nbp=64 col-blocks of 128, 2 halves):
//   or1: (row, cb=2bj+(wc2>>1), half=wc2&1) — unique writer.
//   or2: off-diag, (jrow, cb=2bi+wr2): real half 0, neutral half 1.
// partial[(row*nbp + cb)*2 + half] = {mp, sp, 0, sn}
// ---------------------------------------------------------------------------
__global__ __launch_bounds__(MTHREADS, 2) void k_main_mfma(const ushortT* __restrict__ xn,
                                                           const int* __restrict__ tgt,
                                                           float4* __restrict__ partial,
                                                           int D, int nb) {
  __shared__ ushortT Asm[2][16 * 1024];  // 2 x 32 KB
  __shared__ ushortT Bsm[2][16 * 1024];  // 2 x 32 KB

  const int tid = threadIdx.x;
  const int lane = tid & 63;
  const int w = tid >> 6;             // 0..7

  // --- triangular decode: b -> (bi, bj), bi <= bj  (nb = 32)
  const int b = blockIdx.x;
  int bi = (int)((2.f * nb + 1.f -
                  sqrtf((2.f * nb + 1.f) * (2.f * nb + 1.f) - 8.f * (float)b)) * 0.5f);
  while ((bi + 1) * (2 * nb - bi) / 2 <= b) ++bi;
  while (bi * (2 * nb - bi + 1) / 2 > b) --bi;
  const int bj = bi + (b - bi * (2 * nb - bi + 1) / 2);
  const bool isdiag = (bi == bj);

  const int i0 = bi * 256, j0 = bj * 256;
  const int wr2 = w >> 2;             // 0..1  (128-row half)
  const int wc2 = w & 3;              // 0..3  (64-col quarter)
  const int ib = i0 + wr2 * 128;
  const int jb = j0 + wc2 * 64;
  const int nbp = nb * 2;             // 64 col-blocks of 128 for partial

  // --- staging addresses: lane fetches (row = lane&15, kchunk = lane>>4)
  const int sr = lane & 15, sc = lane >> 4;
  const ushortT* gA0 = xn + (size_t)(i0 + w * 16 + sr) * D + sc * 8;
  const ushortT* gA1 = gA0 + (size_t)128 * D;
  const ushortT* gB0 = xn + (size_t)(j0 + w * 16 + sr) * D + sc * 8;
  const ushortT* gB1 = gB0 + (size_t)128 * D;

  f32x4 acc[8][4];
  #pragma unroll
  for (int mt = 0; mt < 8; ++mt)
    #pragma unroll
    for (int nt = 0; nt < 4; ++nt)
      acc[mt][nt] = (f32x4){0.f, 0.f, 0.f, 0.f};

  const int kiters = D / 64;   // 16
  int cur = 0;

  // prologue: stage tile 0 into buffer 0 (B unconditional)
  {
    async16(gA0, &Asm[0][w * 1024]);
    async16(gA0 + 32, &Asm[0][w * 1024 + 512]);
    async16(gA1, &Asm[0][(w + 8) * 1024]);
    async16(gA1 + 32, &Asm[0][(w + 8) * 1024 + 512]);
    async16(gB0, &Bsm[0][w * 1024]);
    async16(gB0 + 32, &Bsm[0][w * 1024 + 512]);
    async16(gB1, &Bsm[0][(w + 8) * 1024]);
    async16(gB1 + 32, &Bsm[0][(w + 8) * 1024 + 512]);
  }
  __syncthreads();

  for (int kk = 0; kk < kiters; ++kk) {
    if (kk + 1 < kiters) {           // stage tile kk+1 into the other buffer
      const size_t ko = (size_t)(kk + 1) * 64;
      const int nxt = cur ^ 1;
      async16(gA0 + ko, &Asm[nxt][w * 1024]);
      async16(gA0 + ko + 32, &Asm[nxt][w * 1024 + 512]);
      async16(gA1 + ko, &Asm[nxt][(w + 8) * 1024]);
      async16(gA1 + ko + 32, &Asm[nxt][(w + 8) * 1024 + 512]);
      async16(gB0 + ko, &Bsm[nxt][w * 1024]);
      async16(gB0 + ko + 32, &Bsm[nxt][w * 1024 + 512]);
      async16(gB1 + ko, &Bsm[nxt][(w + 8) * 1024]);
      async16(gB1 + ko + 32, &Bsm[nxt][(w + 8) * 1024 + 512]);
    }
    __builtin_amdgcn_sched_barrier(0);   // fence staging region from compute
    const ushortT* Ab = Asm[cur];
    const ushortT* Bb = Bsm[cur];
    #pragma unroll 1
    for (int s = 0; s < 2; ++s) {        // NOT unrolled: bounds frag liveness
      bf16x8 bfr[4];
      #pragma unroll
      for (int nt = 0; nt < 4; ++nt)
        bfr[nt] = *reinterpret_cast<const bf16x8*>(&Bb[(wc2 * 4 + nt) * 1024 + s * 512 + lane * 8]);
      #pragma unroll
      for (int mh = 0; mh < 2; ++mh) {
        bf16x8 afr[4];
        #pragma unroll
        for (int t = 0; t < 4; ++t)
          afr[t] = *reinterpret_cast<const bf16x8*>(&Ab[(wr2 * 8 + mh * 4 + t) * 1024 + s * 512 + lane * 8]);
        #pragma unroll
        for (int t = 0; t < 4; ++t)
          #pragma unroll
          for (int nt = 0; nt < 4; ++nt)
            acc[mh * 4 + t][nt] = __builtin_amdgcn_mfma_f32_16x16x32_bf16(afr[t], bfr[nt], acc[mh * 4 + t][nt], 0, 0, 0);
      }
    }
    __syncthreads();   // drains this iter's stage loads; frees buf[cur] reads
    cur ^= 1;
  }

  // --- epilogue. C/D layout: col = lane&15, row = (lane>>4)*4 + reg
  const int q = lane >> 4, c = lane & 15;
  int tj[4];
  #pragma unroll
  for (int nt = 0; nt < 4; ++nt) tj[nt] = tgt[jb + nt * 16 + c];

  // orientation 1: wave's 128 rows x its 64 cols -> unique (row, cb, half).
  // Two-pass per row (register-lean): pass1 max+negsum, pass2 possum.
  const int cb1 = bj * 2 + (wc2 >> 1);
  const int half1 = wc2 & 1;
  #pragma unroll
  for (int mt = 0; mt < 8; ++mt) {
    const int4 t4 = *reinterpret_cast<const int4*>(tgt + ib + mt * 16 + q * 4);
    const int tiq[4] = {t4.x, t4.y, t4.z, t4.w};
    #pragma unroll
    for (int reg = 0; reg < 4; ++reg) {
      const int i = ib + mt * 16 + q * 4 + reg;
      const int ti = tiq[reg];
      float m = -1e30f, sn = 0.f;
      #pragma unroll
      for (int nt = 0; nt < 4; ++nt) {
        const float s = acc[mt][nt][reg];
        const int j = jb + nt * 16 + c;
        const bool same = (tj[nt] == ti);
        const bool vpos = same && (j != i);
        const float lp = (fminf(s, 1.25f) - 1.25f) * fmaf(s, 64.f, -48.f);
        m = fmaxf(m, vpos ? lp : -2e30f);
        const float ln = (fmaxf(s, -0.25f) + 0.25f) * fmaf(s, 64.f, -16.f);
        const float en = __expf(ln);
        sn += same ? 0.f : en;
      }
      #pragma unroll
      for (int off = 1; off < 16; off <<= 1) m = fmaxf(m, __shfl_xor(m, off));
      float sp = 0.f;
      #pragma unroll
      for (int nt = 0; nt < 4; ++nt) {
        const float s = acc[mt][nt][reg];
        const int j = jb + nt * 16 + c;
        const bool same = (tj[nt] == ti);
        const bool vpos = same && (j != i);
        const float lp = (fminf(s, 1.25f) - 1.25f) * fmaf(s, 64.f, -48.f);
        sp += __expf((vpos ? lp : -2e30f) - m);
      }
      #pragma unroll
      for (int off = 1; off < 16; off <<= 1) {
        sp += __shfl_xor(sp, off);
        sn += __shfl_xor(sn, off);
      }
      if (c == 0) {
        float4 o; o.x = m; o.y = sp; o.z = 0.f; o.w = sn;
        partial[((size_t)i * nbp + cb1) * 2 + half1] = o;
      }
    }
  }

  // orientation 2 (off-diagonal): wave's 64 j-cols, reduced over its 128
  // i-rows -> (jrow, cb=2bi+wr2): real into half 0, neutral into half 1.
  if (!isdiag) {
    const int cb2 = bi * 2 + wr2;
    #pragma unroll
    for (int nt = 0; nt < 4; ++nt) {
      const int jt = tj[nt];
      const int jrow = jb + nt * 16 + c;
      float m = -1e30f, sn = 0.f;
      #pragma unroll
      for (int mt = 0; mt < 8; ++mt) {
        const int4 t4 = *reinterpret_cast<const int4*>(tgt + ib + mt * 16 + q * 4);
        const int tiq[4] = {t4.x, t4.y, t4.z, t4.w};
        #pragma unroll
        for (int reg = 0; reg < 4; ++reg) {
          const float s = acc[mt][nt][reg];
          const bool same = (tiq[reg] == jt);   // j != i guaranteed off-diag
          const float lp = (fminf(s, 1.25f) - 1.25f) * fmaf(s, 64.f, -48.f);
          m = fmaxf(m, same ? lp : -2e30f);
          const float ln = (fmaxf(s, -0.25f) + 0.25f) * fmaf(s, 64.f, -16.f);
          const float en = __expf(ln);
          sn += same ? 0.f : en;
        }
      }
      m = fmaxf(m, __shfl_xor(m, 16));
      m = fmaxf(m, __shfl_xor(m, 32));
      float sp = 0.f;
      #pragma unroll
      for (int mt = 0; mt < 8; ++mt) {
        const int4 t4 = *reinterpret_cast<const int4*>(tgt + ib + mt * 16 + q * 4);
        const int tiq[4] = {t4.x, t4.y, t4.z, t4.w};
        #pragma unroll
        for (int reg = 0; reg < 4; ++reg) {
          const float s = acc[mt][nt][reg];
          const bool same = (tiq[reg] == jt);
          const float lp = (fminf(s, 1.25f) - 1.25f) * fmaf(s, 64.f, -48.f);
          sp += __expf((same ? lp : -2e30f) - m);
        }
      }
      sp += __shfl_xor(sp, 16); sp += __shfl_xor(sp, 32);
      sn += __shfl_xor(sn, 16); sn += __shfl_xor(sn, 32);
      if (lane < 16) {
        float4 o; o.x = m; o.y = sp; o.z = 0.f; o.w = sn;
        partial[((size_t)jrow * nbp + cb2) * 2 + 0] = o;
        float4 z; z.x = -1e30f; z.y = 0.f; z.z = 0.f; z.w = 0.f;
        partial[((size_t)jrow * nbp + cb2) * 2 + 1] = z;
      }
    }
  }
}

// ---------------------------------------------------------------------------
// Kernel C: fold 128 partials per row -> row loss. One wave per row.
// ---------------------------------------------------------------------------
__global__ __launch_bounds__(THREADS) void k_reduce(const float4* __restrict__ partial,
                                                    float* __restrict__ row_loss) {
  const int lane = threadIdx.x & 63;
  const int row = blockIdx.x * 4 + (threadIdx.x >> 6);
  const float4 a = partial[(size_t)row * 128 + lane];
  const float4 b = partial[(size_t)row * 128 + 64 + lane];
  float mp = fmaxf(a.x, b.x);
  float sp = a.y * __expf(a.x - mp) + b.y * __expf(b.x - mp);
  float sn = a.w + b.w;
  #pragma unroll
  for (int off = 1; off < 64; off <<= 1) {
    const float m2 = __shfl_xor(mp, off), s2 = __shfl_xor(sp, off);
    const float nm = fmaxf(mp, m2);
    sp = sp * __expf(mp - nm) + s2 * __expf(m2 - nm);
    mp = nm;
    sn += __shfl_xor(sn, off);
  }
  if (lane == 0) {
    float loss = -1.0f;
    if (sp > 0.f && sn > 0.f) {
      const float z = mp + logf(sp) + logf(sn);
      loss = (z > 0.f) ? (z + log1pf(__expf(-z))) : log1pf(__expf(z));
    }
    row_loss[row] = loss;
  }
}

// ---------------------------------------------------------------------------
// Kernel D: masked mean over rows. One block.
// ---------------------------------------------------------------------------
__global__ __launch_bounds__(THREADS) void k_final(const float* __restrict__ row_loss,
                                                   float* __restrict__ out, int B) {
  __shared__ float ssum[4];
  __shared__ float scnt[4];
  const int tid = threadIdx.x;
  float sum = 0.f, cnt = 0.f;
  for (int i = tid; i < B; i += THREADS) {
    const float l = row_loss[i];
    if (l >= 0.f) { sum += l; cnt += 1.f; }
  }
  #pragma unroll
  for (int off = 32; off; off >>= 1) {
    sum += __shfl_xor(sum, off);
    cnt += __shfl_xor(cnt, off);
  }
  if ((tid & 63) == 0) { ssum[tid >> 6] = sum; scnt[tid >> 6] = cnt; }
  __syncthreads();
  if (tid == 0) {
    float ts = 0.f, tc = 0.f;
    #pragma unroll
    for (int w = 0; w < 4; ++w) { ts += ssum[w]; tc += scnt[w]; }
    out[0] = ts / fmaxf(tc, 1.f);
  }
}

// ---------------------------------------------------------------------------
extern "C" void kernel_launch(void* const* d_in, const int* in_sizes, int n_in,
                              void* d_out, int out_size, void* d_ws, size_t ws_size,
                              hipStream_t stream) {
  const float* x = (const float*)d_in[0];
  const int* tgt = (const int*)d_in[1];
  float* out = (float*)d_out;
  const int B = in_sizes[1];
  const int D = in_sizes[0] / B;
  const int nb128 = B / 128;   // partial stride (unchanged workspace layout)
  const int nb256 = B / 256;   // main-kernel tile count

  ushortT* xn = (ushortT*)d_ws;                                   // B*D bf16 (16 MB)
  float4* partial = (float4*)((char*)d_ws + (size_t)B * D * 2);   // B*2*nb128 float4 (16 MB)
  float* row_loss = (float*)((char*)d_ws + (size_t)B * D * 2 + (size_t)B * 2 * nb128 * 16);

  k_prep<<<B, THREADS, 0, stream>>>(x, xn, D);
  k_main_mfma<<<nb256 * (nb256 + 1) / 2, MTHREADS, 0, stream>>>(xn, tgt, partial, D, nb256);
  k_reduce<<<B / 4, THREADS, 0, stream>>>(partial, row_loss);
  k_final<<<1, THREADS, 0, stream>>>(row_loss, out, B);
}

// Round 13
// 277.887 us; speedup vs baseline: 1.0858x; 1.0858x over previous
//
#include <hip/hip_runtime.h>
#include <hip/hip_bf16.h>
#include <math.h>

#define THREADS 256
#define MTHREADS 1024
typedef unsigned short ushortT;
typedef __attribute__((ext_vector_type(8))) short bf16x8;   // 8 bf16 = 4 VGPRs
typedef __attribute__((ext_vector_type(4))) float f32x4;

__device__ __forceinline__ void async16(const ushortT* g, ushortT* l) {
  __builtin_amdgcn_global_load_lds(
      (const __attribute__((address_space(1))) unsigned int*)g,
      (__attribute__((address_space(3))) unsigned int*)l, 16, 0, 0);
}

__device__ __forceinline__ ushortT f2bf(float f) {
  __hip_bfloat16 h = __float2bfloat16(f);
  return *reinterpret_cast<ushortT*>(&h);
}

// ---------------------------------------------------------------------------
// Kernel A: fused L2-norm + bf16 convert. One block per row (256 thr x float4).
// ---------------------------------------------------------------------------
__global__ __launch_bounds__(THREADS) void k_prep(const float* __restrict__ x,
                                                  ushortT* __restrict__ xn, int D) {
  __shared__ float red[4];
  const int row = blockIdx.x;
  const int tid = threadIdx.x;
  const int gid = row * (D / 4) + tid;
  const float4 v = reinterpret_cast<const float4*>(x)[gid];
  float s = v.x * v.x + v.y * v.y + v.z * v.z + v.w * v.w;
  #pragma unroll
  for (int off = 32; off; off >>= 1) s += __shfl_xor(s, off);
  if ((tid & 63) == 0) red[tid >> 6] = s;
  __syncthreads();
  const float tot = red[0] + red[1] + red[2] + red[3];
  const float rn = 1.0f / fmaxf(sqrtf(tot), 1e-12f);
  ushort4 o;
  o.x = f2bf(v.x * rn); o.y = f2bf(v.y * rn);
  o.z = f2bf(v.z * rn); o.w = f2bf(v.w * rn);
  reinterpret_cast<ushort4*>(xn)[gid] = o;
}

// ---------------------------------------------------------------------------
// Kernel B: triangular 256x256 bf16 MFMA tiles, **16 waves (1024 thr)**, BK=64,
// 2-phase (stage-next before compute, ONE __syncthreads per K-tile).
//
// R12 post-mortem: 512-thr 256² spills STRUCTURALLY (acc=128/lane leaves no
// arch headroom at the 256-reg 2-wave/SIMD budget; 3 attempts, WRITE 60MB).
// Fix = change the acc arithmetic: 1024 thr -> acc = 65536/1024 = 64 regs
// (R0's proven size). 1024-thr blocks force <=128 regs/wave (4 waves/SIMD x
// 128 = 512 pool); K-loop live set 64 acc + 32 frags + ~24 misc ~ 120.
// Per-SIMD MFMA per K-tile = 4 waves x 32 MFMA ~ 2.4k cyc > ~900-cyc load
// latency -> plain __syncthreads 2-phase covers the drain (m230 mechanism).
// Staged bytes: 528 MB (2x less than R9's 1.05 GB).
// SPILL ALARM: WRITE_SIZE > 20 MB -> revert to R9.
//
// Geometry: nb = B/256 = 32, grid 528, wave w in [0,16):
//   wr3 = w>>2 (64-row quarter), wc3 = w&3 (64-col quarter); acc[4][4].
// LDS: dbuf x (A 32K + B 32K) = 128 KB. [buf][group(16 rows)][ksub(2)][512]
// fragment-read order (lane*16B) — 0 bank conflicts (R0-proven map).
// Staging: wave w stages group w of A and of B (4 async16/wave/tile).
// Epilogue -> partial (nbp = 64 col-blocks of 128, 2 halves), NO neutral
// writes needed (16 waves tile all 4 slots):
//   or1: (row, cb=2bj+(wc3>>1), half=wc3&1) — unique writer.
//   or2 off-diag: (jrow, cb=2bi+(wr3>>1), half=wr3&1) — unique writer.
// Coverage: every (row, cb, half) written exactly once across the triangle.
// partial[(row*nbp + cb)*2 + half] = {mp, sp, 0, sn}
// ---------------------------------------------------------------------------
__global__ __launch_bounds__(MTHREADS, 4) void k_main_mfma(const ushortT* __restrict__ xn,
                                                           const int* __restrict__ tgt,
                                                           float4* __restrict__ partial,
                                                           int D, int nb) {
  __shared__ ushortT Asm[2][16 * 1024];  // 2 x 32 KB
  __shared__ ushortT Bsm[2][16 * 1024];  // 2 x 32 KB

  const int tid = threadIdx.x;
  const int lane = tid & 63;
  const int w = tid >> 6;             // 0..15

  // --- triangular decode: b -> (bi, bj), bi <= bj  (nb = 32)
  const int b = blockIdx.x;
  int bi = (int)((2.f * nb + 1.f -
                  sqrtf((2.f * nb + 1.f) * (2.f * nb + 1.f) - 8.f * (float)b)) * 0.5f);
  while ((bi + 1) * (2 * nb - bi) / 2 <= b) ++bi;
  while (bi * (2 * nb - bi + 1) / 2 > b) --bi;
  const int bj = bi + (b - bi * (2 * nb - bi + 1) / 2);
  const bool isdiag = (bi == bj);

  const int i0 = bi * 256, j0 = bj * 256;
  const int wr3 = w >> 2;             // 0..3  (64-row quarter)
  const int wc3 = w & 3;              // 0..3  (64-col quarter)
  const int ib = i0 + wr3 * 64;
  const int jb = j0 + wc3 * 64;
  const int nbp = nb * 2;             // 64 col-blocks of 128 for partial

  // --- staging: wave w stages 16-row group w of A and of B.
  const int sr = lane & 15, sc = lane >> 4;
  const ushortT* gA = xn + (size_t)(i0 + w * 16 + sr) * D + sc * 8;
  const ushortT* gB = xn + (size_t)(j0 + w * 16 + sr) * D + sc * 8;

  f32x4 acc[4][4];
  #pragma unroll
  for (int mt = 0; mt < 4; ++mt)
    #pragma unroll
    for (int nt = 0; nt < 4; ++nt)
      acc[mt][nt] = (f32x4){0.f, 0.f, 0.f, 0.f};

  const int kiters = D / 64;   // 16
  int cur = 0;

  // prologue: stage tile 0 into buffer 0 (B unconditional; diag = same data)
  async16(gA, &Asm[0][w * 1024]);
  async16(gA + 32, &Asm[0][w * 1024 + 512]);
  async16(gB, &Bsm[0][w * 1024]);
  async16(gB + 32, &Bsm[0][w * 1024 + 512]);
  __syncthreads();

  for (int kk = 0; kk < kiters; ++kk) {
    if (kk + 1 < kiters) {           // stage tile kk+1 into the other buffer
      const size_t ko = (size_t)(kk + 1) * 64;
      const int nxt = cur ^ 1;
      async16(gA + ko, &Asm[nxt][w * 1024]);
      async16(gA + ko + 32, &Asm[nxt][w * 1024 + 512]);
      async16(gB + ko, &Bsm[nxt][w * 1024]);
      async16(gB + ko + 32, &Bsm[nxt][w * 1024 + 512]);
    }
    const ushortT* Ab = Asm[cur];
    const ushortT* Bb = Bsm[cur];
    #pragma unroll 1
    for (int s = 0; s < 2; ++s) {    // NOT unrolled: bounds frag liveness
      bf16x8 afr[4];
      #pragma unroll
      for (int mt = 0; mt < 4; ++mt)
        afr[mt] = *reinterpret_cast<const bf16x8*>(&Ab[(wr3 * 4 + mt) * 1024 + s * 512 + lane * 8]);
      bf16x8 bfr[4];
      #pragma unroll
      for (int nt = 0; nt < 4; ++nt)
        bfr[nt] = *reinterpret_cast<const bf16x8*>(&Bb[(wc3 * 4 + nt) * 1024 + s * 512 + lane * 8]);
      #pragma unroll
      for (int mt = 0; mt < 4; ++mt)
        #pragma unroll
        for (int nt = 0; nt < 4; ++nt)
          acc[mt][nt] = __builtin_amdgcn_mfma_f32_16x16x32_bf16(afr[mt], bfr[nt], acc[mt][nt], 0, 0, 0);
    }
    __syncthreads();   // drains this iter's stage loads (issued BEFORE compute
    cur ^= 1;          // -> latency hidden under the 2.4k-cyc MFMA phase)
  }

  // --- epilogue. C/D layout: col = lane&15, row = (lane>>4)*4 + reg
  const int q = lane >> 4, c = lane & 15;
  int tj[4];
  #pragma unroll
  for (int nt = 0; nt < 4; ++nt) tj[nt] = tgt[jb + nt * 16 + c];

  // orientation 1: wave's 64 rows x its 64 cols. Two-pass register-lean.
  const int cb1 = bj * 2 + (wc3 >> 1);
  const int half1 = wc3 & 1;
  #pragma unroll
  for (int mt = 0; mt < 4; ++mt) {
    const int4 t4 = *reinterpret_cast<const int4*>(tgt + ib + mt * 16 + q * 4);
    const int tiq[4] = {t4.x, t4.y, t4.z, t4.w};
    #pragma unroll
    for (int reg = 0; reg < 4; ++reg) {
      const int i = ib + mt * 16 + q * 4 + reg;
      const int ti = tiq[reg];
      float m = -1e30f, sn = 0.f;
      #pragma unroll
      for (int nt = 0; nt < 4; ++nt) {
        const float s = acc[mt][nt][reg];
        const int j = jb + nt * 16 + c;
        const bool same = (tj[nt] == ti);
        const bool vpos = same && (j != i);
        const float lp = (fminf(s, 1.25f) - 1.25f) * fmaf(s, 64.f, -48.f);
        m = fmaxf(m, vpos ? lp : -2e30f);
        const float ln = (fmaxf(s, -0.25f) + 0.25f) * fmaf(s, 64.f, -16.f);
        const float en = __expf(ln);
        sn += same ? 0.f : en;
      }
      #pragma unroll
      for (int off = 1; off < 16; off <<= 1) m = fmaxf(m, __shfl_xor(m, off));
      float sp = 0.f;
      #pragma unroll
      for (int nt = 0; nt < 4; ++nt) {
        const float s = acc[mt][nt][reg];
        const int j = jb + nt * 16 + c;
        const bool same = (tj[nt] == ti);
        const bool vpos = same && (j != i);
        const float lp = (fminf(s, 1.25f) - 1.25f) * fmaf(s, 64.f, -48.f);
        sp += __expf((vpos ? lp : -2e30f) - m);
      }
      #pragma unroll
      for (int off = 1; off < 16; off <<= 1) {
        sp += __shfl_xor(sp, off);
        sn += __shfl_xor(sn, off);
      }
      if (c == 0) {
        float4 o; o.x = m; o.y = sp; o.z = 0.f; o.w = sn;
        partial[((size_t)i * nbp + cb1) * 2 + half1] = o;
      }
    }
  }

  // orientation 2 (off-diagonal): wave's 64 j-cols reduced over its 64
  // i-rows -> (jrow, cb=2bi+(wr3>>1), half=wr3&1). Unique writer, all real.
  if (!isdiag) {
    const int cb2 = bi * 2 + (wr3 >> 1);
    const int half2 = wr3 & 1;
    #pragma unroll
    for (int nt = 0; nt < 4; ++nt) {
      const int jt = tj[nt];
      const int jrow = jb + nt * 16 + c;
      float m = -1e30f, sn = 0.f;
      #pragma unroll
      for (int mt = 0; mt < 4; ++mt) {
        const int4 t4 = *reinterpret_cast<const int4*>(tgt + ib + mt * 16 + q * 4);
        const int tiq[4] = {t4.x, t4.y, t4.z, t4.w};
        #pragma unroll
        for (int reg = 0; reg < 4; ++reg) {
          const float s = acc[mt][nt][reg];
          const bool same = (tiq[reg] == jt);   // j != i guaranteed off-diag
          const float lp = (fminf(s, 1.25f) - 1.25f) * fmaf(s, 64.f, -48.f);
          m = fmaxf(m, same ? lp : -2e30f);
          const float ln = (fmaxf(s, -0.25f) + 0.25f) * fmaf(s, 64.f, -16.f);
          const float en = __expf(ln);
          sn += same ? 0.f : en;
        }
      }
      m = fmaxf(m, __shfl_xor(m, 16));
      m = fmaxf(m, __shfl_xor(m, 32));
      float sp = 0.f;
      #pragma unroll
      for (int mt = 0; mt < 4; ++mt) {
        const int4 t4 = *reinterpret_cast<const int4*>(tgt + ib + mt * 16 + q * 4);
        const int tiq[4] = {t4.x, t4.y, t4.z, t4.w};
        #pragma unroll
        for (int reg = 0; reg < 4; ++reg) {
          const float s = acc[mt][nt][reg];
          const bool same = (tiq[reg] == jt);
          const float lp = (fminf(s, 1.25f) - 1.25f) * fmaf(s, 64.f, -48.f);
          sp += __expf((same ? lp : -2e30f) - m);
        }
      }
      sp += __shfl_xor(sp, 16); sp += __shfl_xor(sp, 32);
      sn += __shfl_xor(sn, 16); sn += __shfl_xor(sn, 32);
      if (lane < 16) {
        float4 o; o.x = m; o.y = sp; o.z = 0.f; o.w = sn;
        partial[((size_t)jrow * nbp + cb2) * 2 + half2] = o;
      }
    }
  }
}

// ---------------------------------------------------------------------------
// Kernel C: fold 128 partials per row -> row loss. One wave per row.
// ---------------------------------------------------------------------------
__global__ __launch_bounds__(THREADS) void k_reduce(const float4* __restrict__ partial,
                                                    float* __restrict__ row_loss) {
  const int lane = threadIdx.x & 63;
  const int row = blockIdx.x * 4 + (threadIdx.x >> 6);
  const float4 a = partial[(size_t)row * 128 + lane];
  const float4 b = partial[(size_t)row * 128 + 64 + lane];
  float mp = fmaxf(a.x, b.x);
  float sp = a.y * __expf(a.x - mp) + b.y * __expf(b.x - mp);
  float sn = a.w + b.w;
  #pragma unroll
  for (int off = 1; off < 64; off <<= 1) {
    const float m2 = __shfl_xor(mp, off), s2 = __shfl_xor(sp, off);
    const float nm = fmaxf(mp, m2);
    sp = sp * __expf(mp - nm) + s2 * __expf(m2 - nm);
    mp = nm;
    sn += __shfl_xor(sn, off);
  }
  if (lane == 0) {
    float loss = -1.0f;
    if (sp > 0.f && sn > 0.f) {
      const float z = mp + logf(sp) + logf(sn);
      loss = (z > 0.f) ? (z + log1pf(__expf(-z))) : log1pf(__expf(z));
    }
    row_loss[row] = loss;
  }
}

// ---------------------------------------------------------------------------
// Kernel D: masked mean over rows. One block.
// ---------------------------------------------------------------------------
__global__ __launch_bounds__(THREADS) void k_final(const float* __restrict__ row_loss,
                                                   float* __restrict__ out, int B) {
  __shared__ float ssum[4];
  __shared__ float scnt[4];
  const int tid = threadIdx.x;
  float sum = 0.f, cnt = 0.f;
  for (int i = tid; i < B; i += THREADS) {
    const float l = row_loss[i];
    if (l >= 0.f) { sum += l; cnt += 1.f; }
  }
  #pragma unroll
  for (int off = 32; off; off >>= 1) {
    sum += __shfl_xor(sum, off);
    cnt += __shfl_xor(cnt, off);
  }
  if ((tid & 63) == 0) { ssum[tid >> 6] = sum; scnt[tid >> 6] = cnt; }
  __syncthreads();
  if (tid == 0) {
    float ts = 0.f, tc = 0.f;
    #pragma unroll
    for (int w = 0; w < 4; ++w) { ts += ssum[w]; tc += scnt[w]; }
    out[0] = ts / fmaxf(tc, 1.f);
  }
}

// ---------------------------------------------------------------------------
extern "C" void kernel_launch(void* const* d_in, const int* in_sizes, int n_in,
                              void* d_out, int out_size, void* d_ws, size_t ws_size,
                              hipStream_t stream) {
  const float* x = (const float*)d_in[0];
  const int* tgt = (const int*)d_in[1];
  float* out = (float*)d_out;
  const int B = in_sizes[1];
  const int D = in_sizes[0] / B;
  const int nb128 = B / 128;   // partial stride (unchanged workspace layout)
  const int nb256 = B / 256;   // main-kernel tile count

  ushortT* xn = (ushortT*)d_ws;                                   // B*D bf16 (16 MB)
  float4* partial = (float4*)((char*)d_ws + (size_t)B * D * 2);   // B*2*nb128 float4 (16 MB)
  float* row_loss = (float*)((char*)d_ws + (size_t)B * D * 2 + (size_t)B * 2 * nb128 * 16);

  k_prep<<<B, THREADS, 0, stream>>>(x, xn, D);
  k_main_mfma<<<nb256 * (nb256 + 1) / 2, MTHREADS, 0, stream>>>(xn, tgt, partial, D, nb256);
  k_reduce<<<B / 4, THREADS, 0, stream>>>(partial, row_loss);
  k_final<<<1, THREADS, 0, stream>>>(row_loss, out, B);
}